// Round 1
// 44846.228 us; speedup vs baseline: 1.1706x; 1.1706x over previous
//
#include <hip/hip_runtime.h>
#include <math.h>

#define TT 512
#define BB 64
#define II 512
#define HH 1024
#define OO 512
#define KK 1536   // I + H

#define GRID 256
#define NTHR 512

// LDS weight strides. WGS: 1540 % 32 == 4 -> gate/cand rows conflict-free.
// Wo stored with a 4-float skew per 256-float K-quarter: quarter q starts at
// q*260 -> banks 0/4/8/12 (+16 for col 1): conflict-free across okq threads.
#define WGS 1540
#define WOS2 1040   // 4 * 260

__device__ __forceinline__ float sigmoidf_(float v) {
    return 1.0f / (1.0f + __expf(-v));
}

// ---- write-through (LLC) store for mutable shared state ----
// Stores must reach the Infinity Cache so other XCDs can see them after the
// barrier; loads are now NORMAL cached loads (L1+L2), made safe by the
// agent-scope acquire fence (buffer_inv) issued inside gbar().
__device__ __forceinline__ void st_sys(float* p, float v) {
    asm volatile("global_store_dword %0, %1, off sc0 sc1"
                 :: "v"(p), "v"(v) : "memory");
}

#define FMA4(av, wv) do { s0 = fmaf((av).x, (wv).x, s0); s1 = fmaf((av).y, (wv).y, s1); \
                          s2 = fmaf((av).z, (wv).z, s2); s3 = fmaf((av).w, (wv).w, s3); } while (0)

// Grid barrier with release/acquire semantics for the cached-load scheme:
//   release: drain this wave's write-through stores (vmcnt 0) before the
//            leader bumps the monotone agent-scope counter;
//   acquire: after the target is reached, every wave invalidates its CU L1 +
//            XCD L2 (buffer_inv sc1 via the agent acquire fence) so normal
//            cached loads refill fresh data from the LLC.
__device__ __forceinline__ void gbar(unsigned* ctr, unsigned target, int tid)
{
    asm volatile("s_waitcnt vmcnt(0)" ::: "memory");
    __syncthreads();
    if (tid == 0) {
        __hip_atomic_fetch_add(ctr, 1u, __ATOMIC_RELAXED, __HIP_MEMORY_SCOPE_AGENT);
        while (__hip_atomic_load(ctr, __ATOMIC_RELAXED, __HIP_MEMORY_SCOPE_AGENT) < target)
            __builtin_amdgcn_s_sleep(2);
    }
    __syncthreads();
    __builtin_amdgcn_fence(__ATOMIC_ACQUIRE, "agent");   // L1+L2 invalidate
}

__global__ void zero_ctr(unsigned* c) { *c = 0u; }

// Persistent kernel, 256 blocks x 512 threads, 1 block/CU (LDS ~84 KB).
// Per block: 8 cols of one gate (z: bid<128, r: bid>=128), 4 candidate cols,
// 2 out cols — weight slices in LDS. 2 custom barriers per step.
// h / hr / zb are read with normal cached loads (L2-coherent via gbar's
// buffer_inv) and written with write-through sc0 sc1 stores.
__global__ __launch_bounds__(NTHR, 2) void gru_fused(
    const float* __restrict__ x,
    const float* __restrict__ Wz, const float* __restrict__ bz,
    const float* __restrict__ Wr, const float* __restrict__ br,
    const float* __restrict__ Wh, const float* __restrict__ bh,
    const float* __restrict__ Wo, const float* __restrict__ bo,
    float* __restrict__ out, float* __restrict__ ws)
{
    __shared__ float wg[8 * WGS];
    __shared__ float wh[4 * WGS];
    __shared__ float wo[2 * WOS2];
    __shared__ float red[NTHR];

    float* h  = ws;                  // [64][1024]
    float* hr = ws + 1 * 65536;      // h * r
    float* zb = ws + 2 * 65536;      // sigmoid(z)
    unsigned* ctr = (unsigned*)(ws + 3 * 65536);

    const int bid = blockIdx.x;
    const int tid = threadIdx.x;

    // ---- stage weight slices to LDS (once; normal cached loads) ----
    const bool is_r = (bid & 128) != 0;
    const float* Wg = is_r ? Wr : Wz;
    const int j0 = (bid & 127) * 8;
    for (int i = tid; i < KK * 8; i += NTHR) {
        int k = i >> 3, jj = i & 7;
        wg[jj * WGS + k] = Wg[(size_t)k * HH + j0 + jj];
    }
    const int j0h = bid * 4;
    for (int i = tid; i < KK * 4; i += NTHR) {
        int k = i >> 2, jj = i & 3;
        wh[jj * WGS + k] = Wh[(size_t)k * HH + j0h + jj];
    }
    const int j0o = bid * 2;
    for (int i = tid; i < HH * 2; i += NTHR) {   // skewed K-quarter layout
        int k = i >> 1, jj = i & 1;
        wo[jj * WOS2 + (k >> 8) * 260 + (k & 255)] = Wo[(size_t)k * OO + j0o + jj];
    }

    // ---- init h = 0 (write-through stores; ws is poisoned 0xAA) ----
    {
        int g = bid * NTHR + tid;
        if (g < BB * HH) st_sys(&h[g], 0.0f);
    }

    // ---- per-thread fixed mappings ----
    const int jj  = tid & 7;
    const int bA  = tid >> 3;
    const int jA  = j0 + jj;
    const float biasA = is_r ? br[jA] : bz[jA];

    const int ocell = tid >> 2;
    const int okq   = tid & 3;
    const int ojo   = ocell & 1;
    const int ob    = ocell >> 1;
    const int jout  = j0o + ojo;
    const float obias = bo[jout];

    const int bc  = tid & 255;
    const int bkh = tid >> 8;
    const int bj  = bc & 3;
    const int bb  = bc >> 2;
    const int jB  = j0h + bj;
    const float biasB = bh[jB];

    unsigned tgt = GRID;
    gbar(ctr, tgt, tid);

    for (int t = 0; t < TT; ++t) {
        const float* xt = x + (size_t)t * BB * II;

        // ================= Phase A =================
        {
            // gate cell: K=1536. x part + h part, both normal cached loads.
            const float* ax   = xt + bA * II;
            const float* wrow = wg + jj * WGS;
            float s0 = 0.f, s1 = 0.f, s2 = 0.f, s3 = 0.f;
            #pragma unroll 8
            for (int q = 0; q < II / 4; ++q) {
                float4 a = *(const float4*)(ax + 4 * q);
                float4 w = *(const float4*)(wrow + 4 * q);
                FMA4(a, w);
            }
            {
                const float4* ah4 = (const float4*)(h + bA * HH);
                const float4* wv2 = (const float4*)(wrow + II);
                #pragma unroll 16
                for (int q = 0; q < 256; ++q) {
                    float4 a = ah4[q];
                    float4 w = wv2[q];
                    FMA4(a, w);
                }
            }
            float val = sigmoidf_(biasA + ((s0 + s1) + (s2 + s3)));
            int idx = bA * HH + jA;
            if (is_r) st_sys(&hr[idx], h[idx] * val);
            else      st_sys(&zb[idx], val);
        }
        {
            // out[t-1] K-quarter partial: h cached, Wo from skewed LDS
            const float4* oh4 = (const float4*)(h + ob * HH + okq * 256);
            const float4* ow4 = (const float4*)(wo + ojo * WOS2 + okq * 260);
            float s0 = 0.f, s1 = 0.f, s2 = 0.f, s3 = 0.f;
            #pragma unroll 16
            for (int q = 0; q < 64; ++q) {
                float4 a = oh4[q];
                float4 w = ow4[q];
                FMA4(a, w);
            }
            red[tid] = (s0 + s1) + (s2 + s3);
            __syncthreads();
            if (okq == 0 && t > 0) {
                float tot = obias + ((red[tid] + red[tid + 1]) +
                                     (red[tid + 2] + red[tid + 3]));
                out[(size_t)(t - 1) * BB * OO + ob * OO + jout] = tot;
            }
        }
        tgt += GRID; gbar(ctr, tgt, tid);

        // ================= Phase B =================
        {
            const float* wrow = wh + bj * WGS;
            const float4* wv  = (const float4*)wrow;
            float s0 = 0.f, s1 = 0.f, s2 = 0.f, s3 = 0.f;
            if (bkh == 0) {
                const float* ax = xt + bb * II;
                #pragma unroll 8
                for (int q = 0; q < II / 4; ++q) {
                    float4 a = *(const float4*)(ax + 4 * q);
                    float4 w = wv[q];
                    FMA4(a, w);
                }
                const float4* ar4 = (const float4*)(hr + bb * HH);
                #pragma unroll 16
                for (int q = 0; q < 64; ++q) {                 // k 512..768
                    float4 a = ar4[q];
                    float4 w = wv[128 + q];
                    FMA4(a, w);
                }
            } else {
                const float4* ar4 = (const float4*)(hr + bb * HH + 256);
                #pragma unroll 16
                for (int q = 0; q < 192; ++q) {                // k 768..1536
                    float4 a = ar4[q];
                    float4 w = wv[192 + q];
                    FMA4(a, w);
                }
            }
            float part = (s0 + s1) + (s2 + s3);
            red[tid] = part;
            __syncthreads();
            if (bkh == 0) {
                float pre = biasB + part + red[tid + 256];
                float cv  = sigmoidf_(pre);
                int idx = bb * HH + jB;
                float z    = zb[idx];
                float hold = h[idx];
                st_sys(&h[idx], z * hold + (1.0f - z) * cv);
            }
        }
        tgt += GRID; gbar(ctr, tgt, tid);
    }

    // ---- tail: out[T-1] = h_{T-1} @ Wo ----
    {
        const float4* oh4 = (const float4*)(h + ob * HH + okq * 256);
        const float4* ow4 = (const float4*)(wo + ojo * WOS2 + okq * 260);
        float s0 = 0.f, s1 = 0.f, s2 = 0.f, s3 = 0.f;
        #pragma unroll 16
        for (int q = 0; q < 64; ++q) {
            float4 a = oh4[q];
            float4 w = ow4[q];
            FMA4(a, w);
        }
        red[tid] = (s0 + s1) + (s2 + s3);
        __syncthreads();
        if (okq == 0) {
            float tot = obias + ((red[tid] + red[tid + 1]) +
                                 (red[tid + 2] + red[tid + 3]));
            out[(size_t)(TT - 1) * BB * OO + ob * OO + jout] = tot;
        }
    }
}

extern "C" void kernel_launch(void* const* d_in, const int* in_sizes, int n_in,
                              void* d_out, int out_size, void* d_ws, size_t ws_size,
                              hipStream_t stream)
{
    (void)in_sizes; (void)n_in; (void)out_size; (void)ws_size;
    const float* x  = (const float*)d_in[0];
    const float* Wz = (const float*)d_in[1];
    const float* bz = (const float*)d_in[2];
    const float* Wr = (const float*)d_in[3];
    const float* br = (const float*)d_in[4];
    const float* Wh = (const float*)d_in[5];
    const float* bh = (const float*)d_in[6];
    const float* Wo = (const float*)d_in[7];
    const float* bo = (const float*)d_in[8];
    float* out = (float*)d_out;
    float* ws  = (float*)d_ws;   // 3*65536 floats state + barrier counter

    zero_ctr<<<1, 1, 0, stream>>>((unsigned*)(ws + 3 * 65536));

    void* args[] = { (void*)&x, (void*)&Wz, (void*)&bz, (void*)&Wr, (void*)&br,
                     (void*)&Wh, (void*)&bh, (void*)&Wo, (void*)&bo,
                     (void*)&out, (void*)&ws };
    hipLaunchCooperativeKernel(reinterpret_cast<void*>(gru_fused),
                               dim3(GRID), dim3(NTHR), args, 0, stream);
}